// Round 7
// baseline (14885.175 us; speedup 1.0000x reference)
//
#include <hip/hip_runtime.h>

// BiLSTM tagger, MI355X. Round 7: latency-shaped k_recurrent.
//  r6 post-mortem: (a) weight-LDS interleave was bank-aliased (bank=rloc*4 -> 8-way,
//  3.4e7 conflicts); (b) exchange = MALL-serviced agent atomics, 256 slots polled by
//  all waves of 64 WGs -> FETCH 252MB of poll traffic and RT on the critical path.
//  v7: WG=128 (2 waves). Wave0 = whole producer chain (matvec fp16-dot2 from LDS with
//  lane-linear [j][lane] layout, in-wave reduce+activation) -> tagged store ~400cy into
//  the step, no prior barrier. Exchange = 4 u64/WG (2 fp16 + tag each, one 64B line per
//  producer). Wave1 polls the 31 remote producers concurrently; own h written to LDS
//  locally. One __syncthreads/step, parity h16 buffers. Pregate ring distance 2.
//  XCD packing: fw on XCD 0-3, bw on 4-7 (heuristic only).
//
// Workspace map (d_ws) ~92.5 MB: same as r6; exbuf reuses hbuf region:
//   [96993280) exbuf  8 KB = [2 dir][2 parity][32 prod][8 u64] (only 4 u64 used/prod)

#define S_LEN 8192
#define LC    16
#define DW    256
#define DC    64
#define HC    128
#define H2    256
#define NG    1024   // 4*H2
#define NTAG  64
#define CV    128
#define PGW   32     // producers (WGs) per direction

typedef _Float16 f16x2 __attribute__((ext_vector_type(2)));
union F4H { float4 f4; f16x2 h2[4]; };

__device__ __forceinline__ float dot2f(f16x2 a, f16x2 b, float c){
#if __has_builtin(__builtin_amdgcn_fdot2)
  return __builtin_amdgcn_fdot2(a, b, c, false);
#else
  return c + (float)a[0]*(float)b[0] + (float)a[1]*(float)b[1];
#endif
}

__device__ __forceinline__ float sigmoid_f(float x){
  return __frcp_rn(1.0f + __expf(-x));
}
__device__ __forceinline__ float tanh_f(float x){
  float a = fabsf(x);
  float t = 1.0f - 2.0f * __frcp_rn(__expf(2.0f*a) + 1.0f);
  return copysignf(t, x);
}

// ---------------------------------------------------------------- k_prep
__global__ __launch_bounds__(512) void k_prep(
    const float* __restrict__ char_emb, const float* __restrict__ char_Wih,
    const float* __restrict__ char_Whh, const float* __restrict__ char_b,
    float* __restrict__ preC, float* __restrict__ whhTc)
{
  int blk = blockIdx.x, tid = threadIdx.x;
  __shared__ float esh[DC];
  if (blk < CV){
    if (tid < DC) esh[tid] = char_emb[blk*DC + tid];
    __syncthreads();
    const float* wr = char_Wih + (size_t)tid*DC;
    float acc = char_b[tid];
#pragma unroll
    for (int d=0; d<DC; d+=4){
      float4 wv = *(const float4*)&wr[d];
      acc += wv.x*esh[d] + wv.y*esh[d+1] + wv.z*esh[d+2] + wv.w*esh[d+3];
    }
    preC[(size_t)blk*512 + tid] = acc;
  } else {
    int k = blk - CV;
    whhTc[(size_t)k*512 + tid] = char_Whh[(size_t)tid*HC + k];
  }
}

// ---------------------------------------------------------------- k_char_lstm
__global__ __launch_bounds__(256) void k_char_lstm(
    const int* __restrict__ charsets, const int* __restrict__ lengths,
    const float* __restrict__ preC, const float* __restrict__ whhTc,
    float* __restrict__ embeds)
{
  int blk = blockIdx.x, tid = threadIdx.x;
  int s0 = blk*16;
  __shared__ float h_sh[16][132];
  __shared__ float gsh[512][17];
  __shared__ int   ch_sh[16];

  for (int i = tid; i < 16*132; i += 256) (&h_sh[0][0])[i] = 0.0f;

  int uw  = tid & 15;
  int ujg = tid >> 4;
  float c[8];
#pragma unroll
  for (int u=0; u<8; u++) c[u] = 0.0f;
  int lw = lengths[s0 + uw];

  int g0 = tid, g1 = tid + 256;
  __syncthreads();

  for (int t=0; t<LC; t++){
    if (tid < 16) ch_sh[tid] = charsets[(size_t)(s0+tid)*LC + t];
    __syncthreads();                                        // (A)

    float acc0[16], acc1[16];
#pragma unroll
    for (int w=0; w<16; w++){
      int ch = ch_sh[w];
      acc0[w] = preC[(size_t)ch*512 + g0];
      acc1[w] = preC[(size_t)ch*512 + g1];
    }
    for (int k4=0; k4<HC; k4+=4){
      float w00 = whhTc[(size_t)(k4+0)*512 + g0];
      float w01 = whhTc[(size_t)(k4+1)*512 + g0];
      float w02 = whhTc[(size_t)(k4+2)*512 + g0];
      float w03 = whhTc[(size_t)(k4+3)*512 + g0];
      float w10 = whhTc[(size_t)(k4+0)*512 + g1];
      float w11 = whhTc[(size_t)(k4+1)*512 + g1];
      float w12 = whhTc[(size_t)(k4+2)*512 + g1];
      float w13 = whhTc[(size_t)(k4+3)*512 + g1];
#pragma unroll
      for (int w=0; w<16; w++){
        float4 h4 = *(const float4*)&h_sh[w][k4];
        acc0[w] += w00*h4.x + w01*h4.y + w02*h4.z + w03*h4.w;
        acc1[w] += w10*h4.x + w11*h4.y + w12*h4.z + w13*h4.w;
      }
    }
#pragma unroll
    for (int w=0; w<16; w++){ gsh[g0][w] = acc0[w]; gsh[g1][w] = acc1[w]; }
    __syncthreads();                                        // (G)

    float hnew[8];
#pragma unroll
    for (int u=0; u<8; u++){
      int j = ujg*8 + u;
      float gi = sigmoid_f(gsh[j][uw]);
      float gf = sigmoid_f(gsh[HC + j][uw]);
      float gg = tanh_f   (gsh[2*HC + j][uw]);
      float go = sigmoid_f(gsh[3*HC + j][uw]);
      c[u] = gf*c[u] + gi*gg;
      hnew[u] = go * tanh_f(c[u]);
    }
#pragma unroll
    for (int u=0; u<8; u+=4)
      *(float4*)&h_sh[uw][ujg*8 + u] = make_float4(hnew[u],hnew[u+1],hnew[u+2],hnew[u+3]);
    if (t == lw-1){
#pragma unroll
      for (int u=0; u<8; u+=4)
        *(float4*)&embeds[(size_t)(s0+uw)*384 + ujg*8 + u]
            = make_float4(hnew[u],hnew[u+1],hnew[u+2],hnew[u+3]);
    }
  }
}

// ---------------------------------------------------------------- k_gather
__global__ __launch_bounds__(256) void k_gather(
    const int* __restrict__ sentence, const float* __restrict__ word_emb,
    float* __restrict__ embeds)
{
  int blk = blockIdx.x, tid = threadIdx.x;
  int s = blk*8 + (tid >> 5);
  int lane = tid & 31;
  int idx = sentence[s];
  const float4* src = (const float4*)(word_emb + (size_t)idx*DW);
  float4* dst = (float4*)(embeds + (size_t)s*384 + 128);
  dst[lane]      = src[lane];
  dst[lane + 32] = src[lane + 32];
}

// ---------------------------------------------------------------- k_pregate
// Output layout: pregates[dir][t][wg=u>>3][q*8 + (u&7)]
__global__ __launch_bounds__(256) void k_pregate(
    const float* __restrict__ embeds,
    const float* __restrict__ Wih_fw, const float* __restrict__ b_fw,
    const float* __restrict__ Wih_bw, const float* __restrict__ b_bw,
    float* __restrict__ pregates)
{
  int dir = blockIdx.z;
  const float* W    = dir ? Wih_bw : Wih_fw;
  const float* bias = dir ? b_bw   : b_fw;
  int t0 = blockIdx.x*64, n0 = blockIdx.y*64;
  __shared__ float a_sh[16][68];
  __shared__ float b_sh[16][68];
  int tid = threadIdx.x;
  int li = tid & 63, kq = tid >> 6;
  int ti = tid >> 4, tj = tid & 15;
  float acc[4][4];
#pragma unroll
  for (int ii=0; ii<4; ii++)
#pragma unroll
    for (int jj=0; jj<4; jj++) acc[ii][jj] = 0.0f;

  for (int k0=0; k0<384; k0+=16){
    float4 av = *(const float4*)&embeds[(size_t)(t0+li)*384 + k0 + kq*4];
    float4 bv = *(const float4*)&W     [(size_t)(n0+li)*384 + k0 + kq*4];
    __syncthreads();
    a_sh[kq*4+0][li]=av.x; a_sh[kq*4+1][li]=av.y; a_sh[kq*4+2][li]=av.z; a_sh[kq*4+3][li]=av.w;
    b_sh[kq*4+0][li]=bv.x; b_sh[kq*4+1][li]=bv.y; b_sh[kq*4+2][li]=bv.z; b_sh[kq*4+3][li]=bv.w;
    __syncthreads();
#pragma unroll
    for (int kk=0; kk<16; kk++){
      float4 a4 = *(const float4*)&a_sh[kk][ti*4];
      float4 b4 = *(const float4*)&b_sh[kk][tj*4];
      float aa[4] = {a4.x,a4.y,a4.z,a4.w};
      float bb[4] = {b4.x,b4.y,b4.z,b4.w};
#pragma unroll
      for (int ii=0; ii<4; ii++)
#pragma unroll
        for (int jj=0; jj<4; jj++) acc[ii][jj] += aa[ii]*bb[jj];
    }
  }
  float4 bias4 = *(const float4*)&bias[n0 + tj*4];
  float bb2[4] = {bias4.x,bias4.y,bias4.z,bias4.w};
  int q = n0 >> 8;
#pragma unroll
  for (int ii=0; ii<4; ii++){
    size_t base = ((size_t)dir*S_LEN + (t0+ti*4+ii))*NG;
#pragma unroll
    for (int jj=0; jj<4; jj++){
      int u = (n0 & 255) + tj*4 + jj;
      pregates[base + (size_t)(u>>3)*32 + q*8 + (u&7)] = acc[ii][jj] + bb2[jj];
    }
  }
}

// ---------------------------------------------------------------- k_recurrent
// 64 WGs x 128 threads. xcd=b&7: dir = xcd>=4; wgi = (b>>3)*4 + (xcd&3). WG owns units
// [wgi*8, wgi*8+8) = 32 gate rows. Wave0 lane l: row r=l>>1 (q=r>>3,u=r&7), k-half
// kh=l&1 (128 k). Weights fp16 in LDS wlds[j][l] (lane-linear b128, conflict-free).
// h fp16 in parity LDS buffers (pad-48 chunks). Wave1 polls remote producers' tagged
// u64 (2 fp16 + tag) while wave0 computes. One __syncthreads per step.
__global__ __launch_bounds__(128) void k_recurrent(
    const float* __restrict__ Whh_fw, const float* __restrict__ Whh_bw,
    const float* __restrict__ pgb_all,
    unsigned long long* __restrict__ exbuf,
    float* __restrict__ hout)
{
  int b = blockIdx.x;                  // 0..63
  int xcd = b & 7;
  int dir = (xcd >= 4) ? 1 : 0;
  int wgi = (b >> 3) * 4 + (xcd & 3);  // 0..31
  int tid = threadIdx.x;
  int w = tid >> 6, l = tid & 63;

  const float* Whh = dir ? Whh_bw : Whh_fw;
  const float* pgb = pgb_all + (size_t)dir * S_LEN * NG;   // [t][32][32]
  unsigned long long* __restrict__ exb = exbuf + (size_t)dir * 2 * PGW * 8;

  __shared__ __align__(16) float4    wlds[16*64];     // [j][l], fp16 payload, 16 KB
  __shared__ __align__(16) _Float16 h16[2][8*48];     // parity; ph(k)=(k>>5)*48+(k&31)

  // ---- stage weights fp32 -> fp16 into wlds[j][l] (thread t: l=t&63, j half t>>6)
  {
    int ls = tid & 63;
    int rs = ls >> 1, khs = ls & 1;
    int qs = rs >> 3, us = rs & 7;
    int R  = qs*H2 + wgi*8 + us;
    const float* wr = Whh + (size_t)R*H2 + khs*128;
    int j0 = (tid >> 6) * 8;
    for (int j=j0; j<j0+8; j++){
      float4 v0 = *(const float4*)&wr[j*8];
      float4 v1 = *(const float4*)&wr[j*8+4];
      F4H p;
      p.h2[0][0]=(_Float16)v0.x; p.h2[0][1]=(_Float16)v0.y;
      p.h2[1][0]=(_Float16)v0.z; p.h2[1][1]=(_Float16)v0.w;
      p.h2[2][0]=(_Float16)v1.x; p.h2[2][1]=(_Float16)v1.y;
      p.h2[3][0]=(_Float16)v1.z; p.h2[3][1]=(_Float16)v1.w;
      wlds[j*64 + ls] = p.f4;
    }
  }
  for (int k = tid; k < H2; k += 128)
    h16[0][(k>>5)*48 + (k&31)] = (_Float16)0.0f;
  __syncthreads();

  int r  = l >> 1, kh = l & 1;
  int q  = r >> 3, u = r & 7;

  float c = 0.0f;
  float pgv = 0.0f, pgn = 0.0f;
  if (w == 0){
    int ta = dir ? (S_LEN-1) : 0;
    int tb = dir ? (S_LEN-2) : 1;
    pgv = pgb[(size_t)ta*NG + wgi*32 + r];
    pgn = pgb[(size_t)tb*NG + wgi*32 + r];
  }

  for (int s=0; s<S_LEN; s++){
    int par = s & 1;
    if (w == 0){
      int t = dir ? (S_LEN-1-s) : s;
      // issue pregate load for s+2 (distance-2 ring; ~2 steps to land)
      int s2 = (s+2 < S_LEN) ? (s+2) : (S_LEN-1);
      int t2 = dir ? (S_LEN-1-s2) : s2;
      float pg2 = pgb[(size_t)t2*NG + wgi*32 + r];

      // matvec: 128-k half-row dot in fp16 (16 chunks of 8)
      const _Float16* hb = h16[par];
      float a0=0.f, a1=0.f, a2=0.f, a3=0.f;
#pragma unroll
      for (int J=0; J<16; J++){
        F4H wv; wv.f4 = wlds[J*64 + l];
        int kc = kh*4 + (J>>2);
        F4H hv; hv.f4 = *(const float4*)&hb[kc*48 + (J&3)*8];
        float acc = (J&3)==0 ? a0 : (J&3)==1 ? a1 : (J&3)==2 ? a2 : a3;
        acc = dot2f(wv.h2[0], hv.h2[0], acc);
        acc = dot2f(wv.h2[1], hv.h2[1], acc);
        acc = dot2f(wv.h2[2], hv.h2[2], acc);
        acc = dot2f(wv.h2[3], hv.h2[3], acc);
        if ((J&3)==0) a0=acc; else if ((J&3)==1) a1=acc; else if ((J&3)==2) a2=acc; else a3=acc;
      }
      float a = (a0+a1)+(a2+a3);
      a += __shfl_xor(a, 1);        // combine the two k-halves of row r
      a += pgv;

      // activation (gate q==2 -> tanh = 2*sigmoid(2x)-1)
      float xxv = (q==2) ? (a+a) : a;
      float sg  = sigmoid_f(xxv);
      float act = (q==2) ? (sg+sg-1.0f) : sg;
      float iA = __shfl(act, u*2);
      float fA = __shfl(act, (8+u)*2);
      float gA = __shfl(act, (16+u)*2);
      float oA = __shfl(act, (24+u)*2);
      c = fA*c + iA*gA;
      float hn = oA * tanh_f(c);
      float hn2 = __shfl(hn, (l+2) & 63);   // partner unit u+1 (valid where used)

      if ((l & 3) == 0 && l < 16){
        int i = l >> 2;                     // 0..3
        f16x2 pr; pr[0] = (_Float16)hn; pr[1] = (_Float16)hn2;
        unsigned lo = *(unsigned*)&pr;
        unsigned long long v =
            ((unsigned long long)(unsigned)(s+1) << 32) | (unsigned long long)lo;
        __hip_atomic_store(&exb[par*(PGW*8) + wgi*8 + i], v,
                           __ATOMIC_RELAXED, __HIP_MEMORY_SCOPE_AGENT);
        int k0 = wgi*8 + 2*i;               // own h -> local LDS (skip MALL RT)
        *(f16x2*)&h16[par^1][(k0>>5)*48 + (k0&31)] = pr;
      }
      if (l < 16 && (l & 1) == 0){
        hout[(size_t)t*512 + dir*H2 + wgi*8 + u] = hn;
      }
      pgv = pgn; pgn = pg2;
    } else {
      // wave 1: poll the 31 remote producers (2 slots/lane), fill h16[par^1]
      unsigned tag = (unsigned)(s+1);
      int p1 = l >> 2, i1 = l & 3;
      int p2 = p1 + 16;
      unsigned long long v1 = 0, v2 = 0;
      bool d1 = (p1 == wgi), d2 = (p2 == wgi);
      unsigned long long* __restrict__ base = &exb[par*(PGW*8)];
      while (!(d1 && d2)){
        if (!d1){
          v1 = __hip_atomic_load(&base[p1*8 + i1], __ATOMIC_RELAXED, __HIP_MEMORY_SCOPE_AGENT);
          d1 = ((unsigned)(v1 >> 32) == tag);
        }
        if (!d2){
          v2 = __hip_atomic_load(&base[p2*8 + i1], __ATOMIC_RELAXED, __HIP_MEMORY_SCOPE_AGENT);
          d2 = ((unsigned)(v2 >> 32) == tag);
        }
      }
      if (p1 != wgi){
        unsigned lo = (unsigned)v1;
        int k0 = p1*8 + 2*i1;
        *(f16x2*)&h16[par^1][(k0>>5)*48 + (k0&31)] = *(f16x2*)&lo;
      }
      if (p2 != wgi){
        unsigned lo = (unsigned)v2;
        int k0 = p2*8 + 2*i1;
        *(f16x2*)&h16[par^1][(k0>>5)*48 + (k0&31)] = *(f16x2*)&lo;
      }
    }
    __syncthreads();   // h16[par^1] complete -> next step's matvec may read it
  }
}

// ---------------------------------------------------------------- k_output
__global__ __launch_bounds__(256) void k_output(
    const float* __restrict__ hout, const float* __restrict__ outW,
    const float* __restrict__ outb, float* __restrict__ out)
{
  __shared__ float wT[128][66];
  __shared__ float hsh[32][132];
  __shared__ float lsh[32][66];
  __shared__ float msh[32][2];
  int t0 = blockIdx.x*32, tid = threadIdx.x;
  int n  = tid & 63, tg = tid >> 6;
  int sl = tid >> 3, kg = tid & 7;
  int wn = tid & 63, wk = tid >> 6;
  float acc[8];
#pragma unroll
  for (int u=0; u<8; u++) acc[u] = 0.0f;

  for (int kc=0; kc<4; kc++){
    int k0 = kc*128;
    float4 wreg[8];
#pragma unroll
    for (int e=0; e<8; e++) wreg[e] = *(const float4*)&outW[(size_t)wn*512 + k0 + wk*32 + e*4];
    float4 hreg[4];
#pragma unroll
    for (int e=0; e<4; e++) hreg[e] = *(const float4*)&hout[(size_t)(t0+sl)*512 + k0 + kg*16 + e*4];
    __syncthreads();
#pragma unroll
    for (int e=0; e<8; e++){
      int kk = wk*32 + e*4;
      wT[kk+0][wn]=wreg[e].x; wT[kk+1][wn]=wreg[e].y; wT[kk+2][wn]=wreg[e].z; wT[kk+3][wn]=wreg[e].w;
    }
#pragma unroll
    for (int e=0; e<4; e++) *(float4*)&hsh[sl][kg*16 + e*4] = hreg[e];
    __syncthreads();
#pragma unroll
    for (int kk4=0; kk4<128; kk4+=4){
      float w0 = wT[kk4+0][n], w1 = wT[kk4+1][n], w2 = wT[kk4+2][n], w3 = wT[kk4+3][n];
#pragma unroll
      for (int u=0; u<8; u++){
        float4 h4 = *(const float4*)&hsh[tg*8+u][kk4];
        acc[u] += w0*h4.x + w1*h4.y + w2*h4.z + w3*h4.w;
      }
    }
  }
  float bn = outb[n];
#pragma unroll
  for (int u=0; u<8; u++) lsh[tg*8+u][n] = acc[u] + bn;
  __syncthreads();
  if (tid < 32){
    float M = -3.4e38f;
    for (int j=0; j<NTAG; j++) M = fmaxf(M, lsh[tid][j]);
    float ssum = 0.0f;
    for (int j=0; j<NTAG; j++) ssum += expf(lsh[tid][j] - M);
    msh[tid][0] = M; msh[tid][1] = logf(ssum);
  }
  __syncthreads();
#pragma unroll
  for (int u=0; u<8; u++){
    int tt = tg*8+u;
    out[(size_t)(t0+tt)*NTAG + n] = lsh[tt][n] - msh[tt][0] - msh[tt][1];
  }
}

// ---------------------------------------------------------------- launch
extern "C" void kernel_launch(void* const* d_in, const int* in_sizes, int n_in,
                              void* d_out, int out_size, void* d_ws, size_t ws_size,
                              hipStream_t stream)
{
  (void)in_sizes; (void)n_in; (void)out_size; (void)ws_size;
  const int*   sentence = (const int*)d_in[0];
  const int*   charsets = (const int*)d_in[1];
  const int*   char_len = (const int*)d_in[2];
  const float* word_emb = (const float*)d_in[3];
  const float* char_emb = (const float*)d_in[4];
  const float* char_Wih = (const float*)d_in[5];
  const float* char_Whh = (const float*)d_in[6];
  const float* char_b   = (const float*)d_in[7];
  const float* fw_Wih   = (const float*)d_in[8];
  const float* fw_Whh   = (const float*)d_in[9];
  const float* fw_b     = (const float*)d_in[10];
  const float* bw_Wih   = (const float*)d_in[11];
  const float* bw_Whh   = (const float*)d_in[12];
  const float* bw_b     = (const float*)d_in[13];
  const float* out_W    = (const float*)d_in[14];
  const float* out_b    = (const float*)d_in[15];
  float* out = (float*)d_out;

  char* ws = (char*)d_ws;
  float* preC     = (float*)(ws);
  float* whhTc    = (float*)(ws + 262144);
  float* embeds   = (float*)(ws + 524288);
  float* pregates = (float*)(ws + 13107200);
  float* houtb    = (float*)(ws + 80216064);
  unsigned long long* exbuf = (unsigned long long*)(ws + 96993280);

  k_prep     <<<256,  512, 0, stream>>>(char_emb, char_Wih, char_Whh, char_b, preC, whhTc);
  k_char_lstm<<<512,  256, 0, stream>>>(charsets, char_len, preC, whhTc, embeds);
  k_gather   <<<1024, 256, 0, stream>>>(sentence, word_emb, embeds);
  k_pregate  <<<dim3(128,16,2), 256, 0, stream>>>(embeds, fw_Wih, fw_b, bw_Wih, bw_b, pregates);
  k_recurrent<<<64,   128, 0, stream>>>(fw_Whh, bw_Whh, pregates, exbuf, houtb);
  k_output   <<<256,  256, 0, stream>>>(houtb, out_W, out_b, out);
}

// Round 9
// 14722.429 us; speedup vs baseline: 1.0111x; 1.0111x over previous
//
#include <hip/hip_runtime.h>

// BiLSTM tagger, MI355X. Round 8 (resubmit; r8 bench was GPUAcquisitionTimeout).
//  Diagnosis across r2-r7: exchange RT ~3-4x theoretical MALL RT. Two taxes:
//  (1) __syncthreads emits s_waitcnt vmcnt(0) -> every step serializes the full
//      store-to-MALL RT inside the barrier. Fix: hand-rolled "lgkmcnt(0); s_barrier"
//      (LDS ordering only; exchange-store correctness carried by tag-in-payload u64 +
//      parity ping-pong, so no vmcnt drain is needed).
//  (2) unthrottled polling contends with the stores at the MALL. Fix: s_sleep(1)
//      backoff, single polling wave, 1 cacheline per producer per step.
//  k_recurrent: 32 WGs (16/dir) x 256 thr. Thread = (unit, gate, 64-k). Weights =
//  32 asm-pinned fp16x2 VGPRs (small enough to hold; r3's failure was 128 floats).
//  h fp16 in LDS, 72-fp16 chunk stride (4 kq lines hit disjoint banks for every J).
//
// Workspace map (d_ws) unchanged (~92.5 MB); exbuf at hbuf region:
//   [96993280) exbuf 4 KB = [2 dir][2 parity][128 u64] (tag32|2xfp16)

#define S_LEN 8192
#define LC    16
#define DW    256
#define DC    64
#define HC    128
#define H2    256
#define NG    1024   // 4*H2
#define NTAG  64
#define CV    128

typedef _Float16 f16x2 __attribute__((ext_vector_type(2)));
union F4H { float4 f4; f16x2 h2[4]; };

__device__ __forceinline__ float dot2f(f16x2 a, f16x2 b, float c){
#if __has_builtin(__builtin_amdgcn_fdot2)
  return __builtin_amdgcn_fdot2(a, b, c, false);
#else
  return c + (float)a[0]*(float)b[0] + (float)a[1]*(float)b[1];
#endif
}

__device__ __forceinline__ float sigmoid_f(float x){
  return __frcp_rn(1.0f + __expf(-x));
}
__device__ __forceinline__ float tanh_f(float x){
  float a = fabsf(x);
  float t = 1.0f - 2.0f * __frcp_rn(__expf(2.0f*a) + 1.0f);
  return copysignf(t, x);
}

// ---------------------------------------------------------------- k_prep
__global__ __launch_bounds__(512) void k_prep(
    const float* __restrict__ char_emb, const float* __restrict__ char_Wih,
    const float* __restrict__ char_Whh, const float* __restrict__ char_b,
    float* __restrict__ preC, float* __restrict__ whhTc)
{
  int blk = blockIdx.x, tid = threadIdx.x;
  __shared__ float esh[DC];
  if (blk < CV){
    if (tid < DC) esh[tid] = char_emb[blk*DC + tid];
    __syncthreads();
    const float* wr = char_Wih + (size_t)tid*DC;
    float acc = char_b[tid];
#pragma unroll
    for (int d=0; d<DC; d+=4){
      float4 wv = *(const float4*)&wr[d];
      acc += wv.x*esh[d] + wv.y*esh[d+1] + wv.z*esh[d+2] + wv.w*esh[d+3];
    }
    preC[(size_t)blk*512 + tid] = acc;
  } else {
    int k = blk - CV;
    whhTc[(size_t)k*512 + tid] = char_Whh[(size_t)tid*HC + k];
  }
}

// ---------------------------------------------------------------- k_char_lstm
__global__ __launch_bounds__(256) void k_char_lstm(
    const int* __restrict__ charsets, const int* __restrict__ lengths,
    const float* __restrict__ preC, const float* __restrict__ whhTc,
    float* __restrict__ embeds)
{
  int blk = blockIdx.x, tid = threadIdx.x;
  int s0 = blk*16;
  __shared__ float h_sh[16][132];
  __shared__ float gsh[512][17];
  __shared__ int   ch_sh[16];

  for (int i = tid; i < 16*132; i += 256) (&h_sh[0][0])[i] = 0.0f;

  int uw  = tid & 15;
  int ujg = tid >> 4;
  float c[8];
#pragma unroll
  for (int u=0; u<8; u++) c[u] = 0.0f;
  int lw = lengths[s0 + uw];

  int g0 = tid, g1 = tid + 256;
  __syncthreads();

  for (int t=0; t<LC; t++){
    if (tid < 16) ch_sh[tid] = charsets[(size_t)(s0+tid)*LC + t];
    __syncthreads();                                        // (A)

    float acc0[16], acc1[16];
#pragma unroll
    for (int w=0; w<16; w++){
      int ch = ch_sh[w];
      acc0[w] = preC[(size_t)ch*512 + g0];
      acc1[w] = preC[(size_t)ch*512 + g1];
    }
    for (int k4=0; k4<HC; k4+=4){
      float w00 = whhTc[(size_t)(k4+0)*512 + g0];
      float w01 = whhTc[(size_t)(k4+1)*512 + g0];
      float w02 = whhTc[(size_t)(k4+2)*512 + g0];
      float w03 = whhTc[(size_t)(k4+3)*512 + g0];
      float w10 = whhTc[(size_t)(k4+0)*512 + g1];
      float w11 = whhTc[(size_t)(k4+1)*512 + g1];
      float w12 = whhTc[(size_t)(k4+2)*512 + g1];
      float w13 = whhTc[(size_t)(k4+3)*512 + g1];
#pragma unroll
      for (int w=0; w<16; w++){
        float4 h4 = *(const float4*)&h_sh[w][k4];
        acc0[w] += w00*h4.x + w01*h4.y + w02*h4.z + w03*h4.w;
        acc1[w] += w10*h4.x + w11*h4.y + w12*h4.z + w13*h4.w;
      }
    }
#pragma unroll
    for (int w=0; w<16; w++){ gsh[g0][w] = acc0[w]; gsh[g1][w] = acc1[w]; }
    __syncthreads();                                        // (G)

    float hnew[8];
#pragma unroll
    for (int u=0; u<8; u++){
      int j = ujg*8 + u;
      float gi = sigmoid_f(gsh[j][uw]);
      float gf = sigmoid_f(gsh[HC + j][uw]);
      float gg = tanh_f   (gsh[2*HC + j][uw]);
      float go = sigmoid_f(gsh[3*HC + j][uw]);
      c[u] = gf*c[u] + gi*gg;
      hnew[u] = go * tanh_f(c[u]);
    }
#pragma unroll
    for (int u=0; u<8; u+=4)
      *(float4*)&h_sh[uw][ujg*8 + u] = make_float4(hnew[u],hnew[u+1],hnew[u+2],hnew[u+3]);
    if (t == lw-1){
#pragma unroll
      for (int u=0; u<8; u+=4)
        *(float4*)&embeds[(size_t)(s0+uw)*384 + ujg*8 + u]
            = make_float4(hnew[u],hnew[u+1],hnew[u+2],hnew[u+3]);
    }
  }
}

// ---------------------------------------------------------------- k_gather
__global__ __launch_bounds__(256) void k_gather(
    const int* __restrict__ sentence, const float* __restrict__ word_emb,
    float* __restrict__ embeds)
{
  int blk = blockIdx.x, tid = threadIdx.x;
  int s = blk*8 + (tid >> 5);
  int lane = tid & 31;
  int idx = sentence[s];
  const float4* src = (const float4*)(word_emb + (size_t)idx*DW);
  float4* dst = (float4*)(embeds + (size_t)s*384 + 128);
  dst[lane]      = src[lane];
  dst[lane + 32] = src[lane + 32];
}

// ---------------------------------------------------------------- k_pregate
// Output layout: pregates[dir][t][wg=u>>4][q*16 + (u&15)]
__global__ __launch_bounds__(256) void k_pregate(
    const float* __restrict__ embeds,
    const float* __restrict__ Wih_fw, const float* __restrict__ b_fw,
    const float* __restrict__ Wih_bw, const float* __restrict__ b_bw,
    float* __restrict__ pregates)
{
  int dir = blockIdx.z;
  const float* W    = dir ? Wih_bw : Wih_fw;
  const float* bias = dir ? b_bw   : b_fw;
  int t0 = blockIdx.x*64, n0 = blockIdx.y*64;
  __shared__ float a_sh[16][68];
  __shared__ float b_sh[16][68];
  int tid = threadIdx.x;
  int li = tid & 63, kq = tid >> 6;
  int ti = tid >> 4, tj = tid & 15;
  float acc[4][4];
#pragma unroll
  for (int ii=0; ii<4; ii++)
#pragma unroll
    for (int jj=0; jj<4; jj++) acc[ii][jj] = 0.0f;

  for (int k0=0; k0<384; k0+=16){
    float4 av = *(const float4*)&embeds[(size_t)(t0+li)*384 + k0 + kq*4];
    float4 bv = *(const float4*)&W     [(size_t)(n0+li)*384 + k0 + kq*4];
    __syncthreads();
    a_sh[kq*4+0][li]=av.x; a_sh[kq*4+1][li]=av.y; a_sh[kq*4+2][li]=av.z; a_sh[kq*4+3][li]=av.w;
    b_sh[kq*4+0][li]=bv.x; b_sh[kq*4+1][li]=bv.y; b_sh[kq*4+2][li]=bv.z; b_sh[kq*4+3][li]=bv.w;
    __syncthreads();
#pragma unroll
    for (int kk=0; kk<16; kk++){
      float4 a4 = *(const float4*)&a_sh[kk][ti*4];
      float4 b4 = *(const float4*)&b_sh[kk][tj*4];
      float aa[4] = {a4.x,a4.y,a4.z,a4.w};
      float bb[4] = {b4.x,b4.y,b4.z,b4.w};
#pragma unroll
      for (int ii=0; ii<4; ii++)
#pragma unroll
        for (int jj=0; jj<4; jj++) acc[ii][jj] += aa[ii]*bb[jj];
    }
  }
  float4 bias4 = *(const float4*)&bias[n0 + tj*4];
  float bb2[4] = {bias4.x,bias4.y,bias4.z,bias4.w};
  int q = n0 >> 8;
#pragma unroll
  for (int ii=0; ii<4; ii++){
    size_t base = ((size_t)dir*S_LEN + (t0+ti*4+ii))*NG;
#pragma unroll
    for (int jj=0; jj<4; jj++){
      int u = (n0 & 255) + tj*4 + jj;
      pregates[base + (size_t)(u>>4)*64 + q*16 + (u&15)] = acc[ii][jj] + bb2[jj];
    }
  }
}

// ---------------------------------------------------------------- k_recurrent
// 32 WGs x 256 thr: dir=b&1, wgi=b>>1 owns units [wgi*16, wgi*16+16).
// Thread (wave w, lane l): unit u4=l>>4 (4/wave), gate q=(l>>2)&3, k-slice kq=l&3 (64 k).
// Weights: 32 pinned fp16x2 VGPRs. h: fp16 LDS, chunk stride 72 (conflict-free).
// Exchange: 8 u64/WG/step (tag32|2xfp16, one 64B line); wave 0 polls with s_sleep
// backoff. Barrier = "lgkmcnt(0); s_barrier" (no vmcnt drain -> store is async).
__global__ __launch_bounds__(256, 1) void k_recurrent(
    const float* __restrict__ Whh_fw, const float* __restrict__ Whh_bw,
    const float* __restrict__ pgb_all,
    unsigned long long* __restrict__ exbuf,
    float* __restrict__ hout)
{
  int b = blockIdx.x;              // 0..31
  int dir = b & 1, wgi = b >> 1;   // 16 WGs per direction
  int tid = threadIdx.x;
  int w = tid >> 6, l = tid & 63;
  int u4 = l >> 4, q = (l >> 2) & 3, kq = l & 3;
  int ul = w*4 + u4;               // unit-in-WG 0..15
  int u  = wgi*16 + ul;            // global unit 0..255
  int row = q*H2 + u;

  const float* Whh = dir ? Whh_bw : Whh_fw;
  const float* pgb = pgb_all + (size_t)dir * S_LEN * NG;   // [t][16][64]
  unsigned long long* __restrict__ exb = exbuf + (size_t)dir * 2 * 128;

  __shared__ _Float16 h16[2][4*72];   // [parity][kq*72 + (k&63)]

  // ---- weights: Whh[row][kq*64 .. +64) as 32 pinned fp16x2 VGPRs
  unsigned wreg[32];
  {
    const float* wr = Whh + (size_t)row*H2 + kq*64;
#pragma unroll
    for (int J=0; J<8; J++){
      float4 v0 = *(const float4*)&wr[J*8];
      float4 v1 = *(const float4*)&wr[J*8+4];
      f16x2 t;
      t[0]=(_Float16)v0.x; t[1]=(_Float16)v0.y; wreg[J*4+0]=__builtin_bit_cast(unsigned,t);
      t[0]=(_Float16)v0.z; t[1]=(_Float16)v0.w; wreg[J*4+1]=__builtin_bit_cast(unsigned,t);
      t[0]=(_Float16)v1.x; t[1]=(_Float16)v1.y; wreg[J*4+2]=__builtin_bit_cast(unsigned,t);
      t[0]=(_Float16)v1.z; t[1]=(_Float16)v1.w; wreg[J*4+3]=__builtin_bit_cast(unsigned,t);
    }
  }
#pragma unroll
  for (int i=0; i<32; i++) asm volatile("" : "+v"(wreg[i]));  // hold in VGPRs

  for (int i = tid; i < 2*4*72; i += 256) (&h16[0][0])[i] = (_Float16)0.0f;
  __syncthreads();

  int pgidx = wgi*64 + q*16 + ul;
  float pgv, pgn;
  {
    int ta = dir ? (S_LEN-1) : 0;
    int tb = dir ? (S_LEN-2) : 1;
    pgv = pgb[(size_t)ta*NG + pgidx];
    pgn = pgb[(size_t)tb*NG + pgidx];
  }
  float c = 0.0f;

  for (int s=0; s<S_LEN; s++){
    int par = s & 1;
    int t = dir ? (S_LEN-1-s) : s;
    int s2 = (s+2 < S_LEN) ? (s+2) : (S_LEN-1);
    int t2 = dir ? (S_LEN-1-s2) : s2;
    float pg2 = pgb[(size_t)t2*NG + pgidx];       // distance-2 ring prefetch

    // matvec: 64-k fp16 dot (8 x b128 h reads, conflict-free)
    const _Float16* hb = h16[par];
    float a0=0.f, a1=0.f, a2=0.f, a3=0.f;
#pragma unroll
    for (int J=0; J<8; J++){
      F4H hv; hv.f4 = *(const float4*)&hb[kq*72 + J*8];
      a0 = dot2f(__builtin_bit_cast(f16x2, wreg[J*4+0]), hv.h2[0], a0);
      a1 = dot2f(__builtin_bit_cast(f16x2, wreg[J*4+1]), hv.h2[1], a1);
      a2 = dot2f(__builtin_bit_cast(f16x2, wreg[J*4+2]), hv.h2[2], a2);
      a3 = dot2f(__builtin_bit_cast(f16x2, wreg[J*4+3]), hv.h2[3], a3);
    }
    float a = (a0+a1)+(a2+a3);
    a += __shfl_xor(a, 1);           // reduce over kq
    a += __shfl_xor(a, 2);
    a += pgv;

    // activation (gate q==2 -> tanh = 2*sigmoid(2x)-1), then within-wave gather
    float xx  = (q==2) ? (a+a) : a;
    float sg  = sigmoid_f(xx);
    float act = (q==2) ? (sg+sg-1.0f) : sg;
    int gb = u4*16;
    float iA = __shfl(act, gb);
    float fA = __shfl(act, gb+4);
    float gA = __shfl(act, gb+8);
    float oA = __shfl(act, gb+12);
    c = fA*c + iA*gA;
    float hn = oA * tanh_f(c);
    float hp = __shfl(hn, (l+16) & 63);   // partner unit's hn (used on l=0,32)

    if ((l & 31) == 0){
      f16x2 pr; pr[0]=(_Float16)hn; pr[1]=(_Float16)hp;
      unsigned lo = __builtin_bit_cast(unsigned, pr);
      if (s+1 < S_LEN){
        unsigned long long v =
            ((unsigned long long)(unsigned)(s+1) << 32) | (unsigned long long)lo;
        __hip_atomic_store(&exb[par*128 + wgi*8 + w*2 + (l>>5)], v,
                           __ATOMIC_RELAXED, __HIP_MEMORY_SCOPE_AGENT);
      }
      int u0 = wgi*16 + w*4 + (l>>5)*2;   // own units -> local LDS (skip MALL RT)
      *(f16x2*)&h16[par^1][(u0>>6)*72 + (u0&63)] = pr;
    }
    if ((l & 15) == 0){
      hout[(size_t)t*512 + dir*H2 + u] = hn;
    }
    pgv = pgn; pgn = pg2;

    if (s+1 < S_LEN){
      if (w == 0){
        // poll 128 u64 (2/lane) with backoff; skip own WG's 8 slots
        unsigned tag = (unsigned)(s+1);
        unsigned long long* __restrict__ sb = &exb[par*128];
        int j1 = l, j2 = l + 64;
        bool d1 = ((j1 >> 3) == wgi), d2 = ((j2 >> 3) == wgi);
        unsigned long long v1 = 0, v2 = 0;
        while (!(d1 && d2)){
          if (!d1){
            v1 = __hip_atomic_load(&sb[j1], __ATOMIC_RELAXED, __HIP_MEMORY_SCOPE_AGENT);
            d1 = ((unsigned)(v1 >> 32) == tag);
          }
          if (!d2){
            v2 = __hip_atomic_load(&sb[j2], __ATOMIC_RELAXED, __HIP_MEMORY_SCOPE_AGENT);
            d2 = ((unsigned)(v2 >> 32) == tag);
          }
          if (!(d1 && d2)) __builtin_amdgcn_s_sleep(1);
        }
        if ((j1 >> 3) != wgi){
          f16x2 pr = __builtin_bit_cast(f16x2, (unsigned)v1);
          int u0 = j1*2;
          *(f16x2*)&h16[par^1][(u0>>6)*72 + (u0&63)] = pr;
        }
        if ((j2 >> 3) != wgi){
          f16x2 pr = __builtin_bit_cast(f16x2, (unsigned)v2);
          int u0 = j2*2;
          *(f16x2*)&h16[par^1][(u0>>6)*72 + (u0&63)] = pr;
        }
      }
      // barrier WITHOUT vmcnt drain: LDS ordering only. Exchange-store correctness
      // is carried by the tagged u64 protocol; global stores drain asynchronously.
      asm volatile("s_waitcnt lgkmcnt(0)\n\ts_barrier" ::: "memory");
    }
  }
}

// ---------------------------------------------------------------- k_output
__global__ __launch_bounds__(256) void k_output(
    const float* __restrict__ hout, const float* __restrict__ outW,
    const float* __restrict__ outb, float* __restrict__ out)
{
  __shared__ float wT[128][66];
  __shared__ float hsh[32][132];
  __shared__ float lsh[32][66];
  __shared__ float msh[32][2];
  int t0 = blockIdx.x*32, tid = threadIdx.x;
  int n  = tid & 63, tg = tid >> 6;
  int sl = tid >> 3, kg = tid & 7;
  int wn = tid & 63, wk = tid >> 6;
  float acc[8];
#pragma unroll
  for (int u=0; u<8; u++) acc[u] = 0.0f;

  for (int kc=0; kc<4; kc++){
    int k0 = kc*128;
    float4 wreg[8];
#pragma unroll
    for (int e=0; e<8; e++) wreg[e] = *(const float4*)&outW[(size_t)wn*512 + k0 + wk*32 + e*4];
    float4 hreg[4];
#pragma unroll
    for (int e=0; e<4; e++) hreg[e] = *(const float4*)&hout[(size_t)(t0+sl)*512 + k0 + kg*16 + e*4];
    __syncthreads();
#pragma unroll
    for (int e=0; e<8; e++){
      int kk = wk*32 + e*4;
      wT[kk+0][wn]=wreg[e].x; wT[kk+1][wn]=wreg[e].y; wT[kk+2][wn]=wreg[e].z; wT[kk+3][wn]=wreg[e].w;
    }
#pragma unroll
    for (int e=0; e<4; e++) *(float4*)&hsh[sl][kg*16 + e*4] = hreg[e];
    __syncthreads();
#pragma unroll
    for (int kk4=0; kk4<128; kk4+=4){
      float w0 = wT[kk4+0][n], w1 = wT[kk4+1][n], w2 = wT[kk4+2][n], w3 = wT[kk4+3][n];
#pragma unroll
      for (int u=0; u<8; u++){
        float4 h4 = *(const float4*)&hsh[tg*8+u][kk4];
        acc[u] += w0*h4.x + w1*h4.y + w2*h4.z + w3*h4.w;
      }
    }
  }
  float bn = outb[n];
#pragma unroll
  for (int u=0; u<8; u++) lsh[tg*8+u][n] = acc[u] + bn;
  __syncthreads();
  if (tid < 32){
    float M = -3.4e38f;
    for (int j=0; j<NTAG; j++) M = fmaxf(M, lsh[tid][j]);
    float ssum = 0.0f;
    for (int j=0; j<NTAG; j++) ssum += expf(lsh[tid][j] - M);
    msh[tid][0] = M; msh[tid][1] = logf(ssum);
  }
  __syncthreads();
#pragma unroll
  for (int u=0; u<8; u++){
    int tt = tg*8+u;
    out[(size_t)(t0+tt)*NTAG + n] = lsh[tt][n] - msh[tt][0] - msh[tt][1];
  }
}

// ---------------------------------------------------------------- launch
extern "C" void kernel_launch(void* const* d_in, const int* in_sizes, int n_in,
                              void* d_out, int out_size, void* d_ws, size_t ws_size,
                              hipStream_t stream)
{
  (void)in_sizes; (void)n_in; (void)out_size; (void)ws_size;
  const int*   sentence = (const int*)d_in[0];
  const int*   charsets = (const int*)d_in[1];
  const int*   char_len = (const int*)d_in[2];
  const float* word_emb = (const float*)d_in[3];
  const float* char_emb = (const float*)d_in[4];
  const float* char_Wih = (const float*)d_in[5];
  const float* char_Whh = (const float*)d_in[6];
  const float* char_b   = (const float*)d_in[7];
  const float* fw_Wih   = (const float*)d_in[8];
  const float* fw_Whh   = (const float*)d_in[9];
  const float* fw_b     = (const float*)d_in[10];
  const float* bw_Wih   = (const float*)d_in[11];
  const float* bw_Whh   = (const float*)d_in[12];
  const float* bw_b     = (const float*)d_in[13];
  const float* out_W    = (const float*)d_in[14];
  const float* out_b    = (const float*)d_in[15];
  float* out = (float*)d_out;

  char* ws = (char*)d_ws;
  float* preC     = (float*)(ws);
  float* whhTc    = (float*)(ws + 262144);
  float* embeds   = (float*)(ws + 524288);
  float* pregates = (float*)(ws + 13107200);
  float* houtb    = (float*)(ws + 80216064);
  unsigned long long* exbuf = (unsigned long long*)(ws + 96993280);

  k_prep     <<<256,  512, 0, stream>>>(char_emb, char_Wih, char_Whh, char_b, preC, whhTc);
  k_char_lstm<<<512,  256, 0, stream>>>(charsets, char_len, preC, whhTc, embeds);
  k_gather   <<<1024, 256, 0, stream>>>(sentence, word_emb, embeds);
  k_pregate  <<<dim3(128,16,2), 256, 0, stream>>>(embeds, fw_Wih, fw_b, bw_Wih, bw_b, pregates);
  k_recurrent<<<32,   256, 0, stream>>>(fw_Whh, bw_Whh, pregates, exbuf, houtb);
  k_output   <<<256,  256, 0, stream>>>(houtb, out_W, out_b, out);
}